// Round 2
// baseline (221.866 us; speedup 1.0000x reference)
//
#include <hip/hip_runtime.h>
#include <math.h>

#define B_ 64
#define H_ 256
#define W_ 256
#define C_ 3
#define K_ 20

// ws layout (floats/ints):
//   coefs:  B*8 floats  @ byte 0      (a0,a1,a2,b0,b1,b2,pad,pad)
//   sums :  B*4 floats  @ byte 2048   (r,g,b,pad) accumulators
//   rects:  B*K*4 ints  @ byte 3072   (y0c,x0c,y1,x1)
#define WS_COEFS 0
#define WS_SUMS  2048
#define WS_RECTS 3072

// Coalesced streaming pass: pulls the 50 MB images buffer into L3 (Infinity
// Cache) at ~5-6 TB/s so the subsequent gather pass hits cache instead of
// taking ~900-cycle HBM misses on 12-byte scattered requests.
// asm sink keeps the load live (no DCE) without any store traffic.
__global__ __launch_bounds__(256) void prefetch_kernel(const float4* __restrict__ images)
{
    size_t i = (size_t)blockIdx.x * 256 + threadIdx.x;  // 12288 blocks cover 3145728 float4
    float4 v = images[i];
    float acc = v.x + v.y + v.z + v.w;
    asm volatile("" :: "v"(acc));
}

__global__ __launch_bounds__(32) void prep_kernel(
    const float* __restrict__ zoom, const float* __restrict__ rot,
    const float* __restrict__ shy,  const float* __restrict__ ty,
    const float* __restrict__ tx,
    const int* __restrict__ hs, const int* __restrict__ ws,
    const int* __restrict__ y0, const int* __restrict__ x0,
    float* __restrict__ coefs, float* __restrict__ sums, int* __restrict__ rects)
{
    int b = blockIdx.x;
    int t = threadIdx.x;
    if (t == 0) {
        float zo = zoom[b], ro = rot[b], sh = shy[b];
        float tyv = ty[b], txv = tx[b];
        float si, co;
        __sincosf(ro, &si, &co);
        const float cx = (W_ - 1) * 0.5f, cy = (H_ - 1) * 0.5f;
        float a0 = zo * co;
        float a1 = -zo * (si + sh);
        float b0 = zo * si;
        float b1 = zo * co;
        float a2 = -a0 * cx - a1 * cy + cx + txv;
        float b2 = -b0 * cx - b1 * cy + cy + tyv;
        float* cf = coefs + b * 8;
        cf[0] = a0; cf[1] = a1; cf[2] = a2;
        cf[3] = b0; cf[4] = b1; cf[5] = b2;
        sums[b * 4 + 0] = 0.f;
        sums[b * 4 + 1] = 0.f;
        sums[b * 4 + 2] = 0.f;
        sums[b * 4 + 3] = 0.f;
    }
    if (t < K_) {
        int i = b * K_ + t;
        int h = hs[i], w = ws[i];
        int yy = min(y0[i], H_ - h);
        int xx = min(x0[i], W_ - w);
        int* r = rects + i * 4;
        r[0] = yy; r[1] = xx; r[2] = yy + h; r[3] = xx + w;
    }
}

__device__ __forceinline__ float3 bilinear_sample(const float* __restrict__ img,
                                                  float xs, float ys)
{
    float x0f = floorf(xs), y0f = floorf(ys);
    float wx = xs - x0f, wy = ys - y0f;
    int ix0 = (int)x0f, iy0 = (int)y0f;
    int ix1 = ix0 + 1, iy1 = iy0 + 1;
    float vx0 = ((unsigned)ix0 < (unsigned)W_) ? 1.f : 0.f;
    float vx1 = ((unsigned)ix1 < (unsigned)W_) ? 1.f : 0.f;
    float vy0 = ((unsigned)iy0 < (unsigned)H_) ? 1.f : 0.f;
    float vy1 = ((unsigned)iy1 < (unsigned)H_) ? 1.f : 0.f;
    int cx0 = min(max(ix0, 0), W_ - 1), cx1 = min(max(ix1, 0), W_ - 1);
    int cy0 = min(max(iy0, 0), H_ - 1), cy1 = min(max(iy1, 0), H_ - 1);
    float w00 = (1.f - wy) * (1.f - wx) * vy0 * vx0;
    float w01 = (1.f - wy) * wx * vy0 * vx1;
    float w10 = wy * (1.f - wx) * vy1 * vx0;
    float w11 = wy * wx * vy1 * vx1;
    const float* p00 = img + (cy0 * W_ + cx0) * 3;
    const float* p01 = img + (cy0 * W_ + cx1) * 3;
    const float* p10 = img + (cy1 * W_ + cx0) * 3;
    const float* p11 = img + (cy1 * W_ + cx1) * 3;
    float3 r;
    r.x = w00 * p00[0] + w01 * p01[0] + w10 * p10[0] + w11 * p11[0];
    r.y = w00 * p00[1] + w01 * p01[1] + w10 * p10[1] + w11 * p11[1];
    r.z = w00 * p00[2] + w01 * p01[2] + w10 * p10[2] + w11 * p11[2];
    return r;
}

__global__ __launch_bounds__(256) void sum_kernel(
    const float* __restrict__ images, const float* __restrict__ coefs,
    float* __restrict__ sums)
{
    int b = blockIdx.y;
    const float* cf = coefs + b * 8;
    float a0 = cf[0], a1 = cf[1], a2 = cf[2];
    float b0 = cf[3], b1 = cf[4], b2 = cf[5];
    int p = blockIdx.x * 256 + threadIdx.x;
    float fy = (float)(p >> 8), fx = (float)(p & 255);
    float xs = a0 * fx + a1 * fy + a2;
    float ys = b0 * fx + b1 * fy + b2;
    const float* img = images + (size_t)b * (H_ * W_ * 3);
    float3 v = bilinear_sample(img, xs, ys);
    float s0 = v.x, s1 = v.y, s2 = v.z;
    for (int o = 32; o > 0; o >>= 1) {
        s0 += __shfl_down(s0, o);
        s1 += __shfl_down(s1, o);
        s2 += __shfl_down(s2, o);
    }
    __shared__ float red[4][3];
    int wave = threadIdx.x >> 6, lane = threadIdx.x & 63;
    if (lane == 0) { red[wave][0] = s0; red[wave][1] = s1; red[wave][2] = s2; }
    __syncthreads();
    if (threadIdx.x == 0) {
        float t0 = red[0][0] + red[1][0] + red[2][0] + red[3][0];
        float t1 = red[0][1] + red[1][1] + red[2][1] + red[3][1];
        float t2 = red[0][2] + red[1][2] + red[2][2] + red[3][2];
        atomicAdd(&sums[b * 4 + 0], t0);
        atomicAdd(&sums[b * 4 + 1], t1);
        atomicAdd(&sums[b * 4 + 2], t2);
    }
}

__global__ __launch_bounds__(256) void apply_kernel(
    const float* __restrict__ images, const float* __restrict__ coefs,
    const float* __restrict__ sums, const int* __restrict__ rects,
    const float* __restrict__ fill, const float* __restrict__ contrast,
    const float* __restrict__ brightness, float* __restrict__ out)
{
    int b = blockIdx.y;
    __shared__ int s_rect[K_ * 4];
    __shared__ float s_fill[K_];
    __shared__ float sbuf[768];

    if (threadIdx.x < K_ * 4) s_rect[threadIdx.x] = rects[b * K_ * 4 + threadIdx.x];
    if (threadIdx.x < K_)     s_fill[threadIdx.x] = fill[b * K_ + threadIdx.x];

    const float* cf = coefs + b * 8;
    float a0 = cf[0], a1 = cf[1], a2 = cf[2];
    float b0 = cf[3], b1 = cf[4], b2 = cf[5];
    float ctr = contrast[b], br = brightness[b];
    float m0 = sums[b * 4 + 0] * (1.f / 65536.f);
    float m1 = sums[b * 4 + 1] * (1.f / 65536.f);
    float m2 = sums[b * 4 + 2] * (1.f / 65536.f);

    int p = blockIdx.x * 256 + threadIdx.x;
    int y = p >> 8, x = p & 255;
    float fy = (float)y, fx = (float)x;
    float xs = a0 * fx + a1 * fy + a2;
    float ys = b0 * fx + b1 * fy + b2;
    const float* img = images + (size_t)b * (H_ * W_ * 3);
    float3 v = bilinear_sample(img, xs, ys);

    v.x = (v.x - m0) * ctr + m0 + br;
    v.y = (v.y - m1) * ctr + m1 + br;
    v.z = (v.z - m2) * ctr + m2 + br;

    __syncthreads();  // s_rect / s_fill ready

    bool erase = false, blot = false;
#pragma unroll
    for (int k = 0; k < K_; k++) {
        bool cov = (y >= s_rect[4 * k + 0]) & (y < s_rect[4 * k + 2]) &
                   (x >= s_rect[4 * k + 1]) & (x < s_rect[4 * k + 3]);
        if (cov) {
            if (s_fill[k] != 0.f) blot = true;
            else erase = true;
        }
    }
    float r0 = blot ? 1.f : (erase ? 0.f : fminf(fmaxf(v.x, 0.f), 1.f));
    float r1 = blot ? 1.f : (erase ? 0.f : fminf(fmaxf(v.y, 0.f), 1.f));
    float r2 = blot ? 1.f : (erase ? 0.f : fminf(fmaxf(v.z, 0.f), 1.f));

    sbuf[threadIdx.x * 3 + 0] = r0;
    sbuf[threadIdx.x * 3 + 1] = r1;
    sbuf[threadIdx.x * 3 + 2] = r2;
    __syncthreads();

    // 768 floats = 192 float4, block-contiguous and 16B-aligned
    float* ob = out + ((size_t)b * 65536 + (size_t)blockIdx.x * 256) * 3;
    if (threadIdx.x < 192)
        ((float4*)ob)[threadIdx.x] = ((const float4*)sbuf)[threadIdx.x];
}

extern "C" void kernel_launch(void* const* d_in, const int* in_sizes, int n_in,
                              void* d_out, int out_size, void* d_ws, size_t ws_size,
                              hipStream_t stream) {
    const float* images     = (const float*)d_in[0];
    const float* zoom       = (const float*)d_in[1];
    const float* rot        = (const float*)d_in[2];
    const float* shy        = (const float*)d_in[3];
    const float* ty         = (const float*)d_in[4];
    const float* tx         = (const float*)d_in[5];
    const float* contrast   = (const float*)d_in[6];
    const float* brightness = (const float*)d_in[7];
    const float* fill       = (const float*)d_in[8];
    const int*   hs         = (const int*)d_in[9];
    const int*   ws_        = (const int*)d_in[10];
    const int*   y0         = (const int*)d_in[11];
    const int*   x0         = (const int*)d_in[12];
    float* out = (float*)d_out;

    char* wsb = (char*)d_ws;
    float* coefs = (float*)(wsb + WS_COEFS);
    float* sums  = (float*)(wsb + WS_SUMS);
    int*   rects = (int*)(wsb + WS_RECTS);

    // Warm L3 with a coalesced stream of images first (perf-only, no deps).
    prefetch_kernel<<<(B_ * H_ * W_ * C_ / 4) / 256, 256, 0, stream>>>((const float4*)images);
    prep_kernel<<<B_, 32, 0, stream>>>(zoom, rot, shy, ty, tx,
                                       hs, ws_, y0, x0, coefs, sums, rects);
    dim3 grid(H_ * W_ / 256, B_);
    sum_kernel<<<grid, 256, 0, stream>>>(images, coefs, sums);
    apply_kernel<<<grid, 256, 0, stream>>>(images, coefs, sums, rects, fill,
                                           contrast, brightness, out);
}

// Round 3
// 102.428 us; speedup vs baseline: 2.1661x; 2.1661x over previous
//
#include <hip/hip_runtime.h>
#include <math.h>

#define B_ 64
#define H_ 256
#define W_ 256
#define K_ 20

#define TILE_  32
#define WINW   48   // >= ceil((1.15+0.2875)*31)+2 = 47
#define WINH   40   // >= ceil((0.0575+1.15)*31)+2 = 40
#define PLANE  (WINW * WINH)   // 1920 floats per channel plane

// ws layout:
//   coefs:  B*8 floats  @ byte 0
//   sums :  B*4 floats  @ byte 2048
//   rects:  B*K*4 ints  @ byte 3072
#define WS_COEFS 0
#define WS_SUMS  2048
#define WS_RECTS 3072

__global__ __launch_bounds__(32) void prep_kernel(
    const float* __restrict__ zoom, const float* __restrict__ rot,
    const float* __restrict__ shy,  const float* __restrict__ ty,
    const float* __restrict__ tx,
    const int* __restrict__ hs, const int* __restrict__ ws,
    const int* __restrict__ y0, const int* __restrict__ x0,
    float* __restrict__ coefs, float* __restrict__ sums, int* __restrict__ rects)
{
    int b = blockIdx.x;
    int t = threadIdx.x;
    if (t == 0) {
        float zo = zoom[b], ro = rot[b], sh = shy[b];
        float tyv = ty[b], txv = tx[b];
        float si, co;
        __sincosf(ro, &si, &co);
        const float cx = (W_ - 1) * 0.5f, cy = (H_ - 1) * 0.5f;
        float a0 = zo * co;
        float a1 = -zo * (si + sh);
        float b0 = zo * si;
        float b1 = zo * co;
        float a2 = -a0 * cx - a1 * cy + cx + txv;
        float b2 = -b0 * cx - b1 * cy + cy + tyv;
        float* cf = coefs + b * 8;
        cf[0] = a0; cf[1] = a1; cf[2] = a2;
        cf[3] = b0; cf[4] = b1; cf[5] = b2;
        sums[b * 4 + 0] = 0.f;
        sums[b * 4 + 1] = 0.f;
        sums[b * 4 + 2] = 0.f;
        sums[b * 4 + 3] = 0.f;
    }
    if (t < K_) {
        int i = b * K_ + t;
        int h = hs[i], w = ws[i];
        int yy = min(y0[i], H_ - h);
        int xx = min(x0[i], W_ - w);
        int* r = rects + i * 4;
        r[0] = yy; r[1] = xx; r[2] = yy + h; r[3] = xx + w;
    }
}

// Pass A: per 32x32 output tile, stage the (provably bounded) 48x40 source
// window into LDS with coalesced loads, bilinear-sample from LDS, write the
// raw warped image to `out`, accumulate per-image channel sums.
__global__ __launch_bounds__(256) void warp_sum_kernel(
    const float* __restrict__ images, const float* __restrict__ coefs,
    float* __restrict__ sums, float* __restrict__ out)
{
    int b  = blockIdx.y;
    int tx = blockIdx.x >> 3;     // column-major tile order: consecutive blocks
    int ty = blockIdx.x & 7;      // share the (wider) x-overlap within an XCD
    int X0 = tx * TILE_, Y0 = ty * TILE_;

    const float* cf = coefs + b * 8;
    float a0 = cf[0], a1 = cf[1], a2 = cf[2];
    float b0 = cf[3], b1 = cf[4], b2 = cf[5];

    float X1 = (float)(X0 + 31), Y1f = (float)(Y0 + 31);
    float X0f = (float)X0, Y0f = (float)Y0;
    float xsmin = a2 + fminf(a0 * X0f, a0 * X1) + fminf(a1 * Y0f, a1 * Y1f);
    float ysmin = b2 + fminf(b0 * X0f, b0 * X1) + fminf(b1 * Y0f, b1 * Y1f);
    int wx0 = min(max((int)floorf(xsmin), 0), W_ - WINW);   // window always
    int wy0 = min(max((int)floorf(ysmin), 0), H_ - WINH);   // fully in-image

    __shared__ float lds[3 * PLANE];
    __shared__ float red[4][3];
    const float* img = images + (size_t)b * (H_ * W_ * 3);

    // stage: 1920 pixels, 3 floats each; consecutive threads -> consecutive
    // pixels within a row segment -> coalesced 576B row chunks
    for (int i = threadIdx.x; i < PLANE; i += 256) {
        int r = i / WINW, px = i - r * WINW;
        const float* s = img + (((wy0 + r) << 8) + wx0 + px) * 3;
        lds[i]             = s[0];
        lds[PLANE + i]     = s[1];
        lds[2 * PLANE + i] = s[2];
    }
    __syncthreads();

    float s0 = 0.f, s1 = 0.f, s2 = 0.f;
#pragma unroll
    for (int k = 0; k < 4; k++) {
        int q  = k * 256 + threadIdx.x;
        int ly = q >> 5, lx = q & 31;
        float fx = (float)(X0 + lx), fy = (float)(Y0 + ly);
        float xs = a0 * fx + a1 * fy + a2;
        float ys = b0 * fx + b1 * fy + b2;
        float xf = floorf(xs), yf = floorf(ys);
        float wx = xs - xf, wy = ys - yf;
        int ix0 = (int)xf, iy0 = (int)yf;
        float vx0 = ((unsigned)ix0       < (unsigned)W_) ? 1.f : 0.f;
        float vx1 = ((unsigned)(ix0 + 1) < (unsigned)W_) ? 1.f : 0.f;
        float vy0 = ((unsigned)iy0       < (unsigned)H_) ? 1.f : 0.f;
        float vy1 = ((unsigned)(iy0 + 1) < (unsigned)H_) ? 1.f : 0.f;
        // window-relative clamped coords (defensively clamped into capacity)
        int rx0 = min(max(min(max(ix0, 0), W_ - 1) - wx0, 0), WINW - 1);
        int rx1 = min(max(min(max(ix0 + 1, 0), W_ - 1) - wx0, 0), WINW - 1);
        int ry0 = min(max(min(max(iy0, 0), H_ - 1) - wy0, 0), WINH - 1);
        int ry1 = min(max(min(max(iy0 + 1, 0), H_ - 1) - wy0, 0), WINH - 1);
        int i00 = ry0 * WINW + rx0, i01 = ry0 * WINW + rx1;
        int i10 = ry1 * WINW + rx0, i11 = ry1 * WINW + rx1;
        float w00 = (1.f - wy) * (1.f - wx) * vy0 * vx0;
        float w01 = (1.f - wy) * wx * vy0 * vx1;
        float w10 = wy * (1.f - wx) * vy1 * vx0;
        float w11 = wy * wx * vy1 * vx1;
        float r0 = w00 * lds[i00] + w01 * lds[i01] + w10 * lds[i10] + w11 * lds[i11];
        float r1 = w00 * lds[PLANE + i00] + w01 * lds[PLANE + i01] +
                   w10 * lds[PLANE + i10] + w11 * lds[PLANE + i11];
        float r2 = w00 * lds[2 * PLANE + i00] + w01 * lds[2 * PLANE + i01] +
                   w10 * lds[2 * PLANE + i10] + w11 * lds[2 * PLANE + i11];
        s0 += r0; s1 += r1; s2 += r2;
        float* op = out + (size_t)(((b << 16) + ((Y0 + ly) << 8) + X0 + lx)) * 3;
        op[0] = r0; op[1] = r1; op[2] = r2;
    }

    for (int o = 32; o > 0; o >>= 1) {
        s0 += __shfl_down(s0, o);
        s1 += __shfl_down(s1, o);
        s2 += __shfl_down(s2, o);
    }
    int wave = threadIdx.x >> 6, lane = threadIdx.x & 63;
    if (lane == 0) { red[wave][0] = s0; red[wave][1] = s1; red[wave][2] = s2; }
    __syncthreads();
    if (threadIdx.x == 0) {
        atomicAdd(&sums[b * 4 + 0], red[0][0] + red[1][0] + red[2][0] + red[3][0]);
        atomicAdd(&sums[b * 4 + 1], red[0][1] + red[1][1] + red[2][1] + red[3][1]);
        atomicAdd(&sums[b * 4 + 2], red[0][2] + red[1][2] + red[2][2] + red[3][2]);
    }
}

// Pass B: in-place streaming over `out`: contrast/brightness/cutout/clip.
// One block per output row; float4 LDS-staged load and store.
__global__ __launch_bounds__(256) void finish_kernel(
    float* __restrict__ out, const float* __restrict__ sums,
    const int* __restrict__ rects, const float* __restrict__ fill,
    const float* __restrict__ contrast, const float* __restrict__ brightness)
{
    int b = blockIdx.x >> 8;
    int y = blockIdx.x & 255;
    int x = threadIdx.x;

    __shared__ float sbuf[768];
    __shared__ int   s_rect[K_ * 4];
    __shared__ float s_fill[K_];

    float* rowp = out + (size_t)blockIdx.x * 768;
    if (threadIdx.x < 192)
        ((float4*)sbuf)[threadIdx.x] = ((const float4*)rowp)[threadIdx.x];
    if (threadIdx.x < K_ * 4) s_rect[threadIdx.x] = rects[b * K_ * 4 + threadIdx.x];
    if (threadIdx.x < K_)     s_fill[threadIdx.x] = fill[b * K_ + threadIdx.x];
    __syncthreads();

    float ctr = contrast[b], br = brightness[b];
    float m0 = sums[b * 4 + 0] * (1.f / 65536.f);
    float m1 = sums[b * 4 + 1] * (1.f / 65536.f);
    float m2 = sums[b * 4 + 2] * (1.f / 65536.f);

    float v0 = (sbuf[x * 3 + 0] - m0) * ctr + m0 + br;
    float v1 = (sbuf[x * 3 + 1] - m1) * ctr + m1 + br;
    float v2 = (sbuf[x * 3 + 2] - m2) * ctr + m2 + br;

    bool erase = false, blot = false;
#pragma unroll
    for (int k = 0; k < K_; k++) {
        bool cov = (y >= s_rect[4 * k + 0]) & (y < s_rect[4 * k + 2]) &
                   (x >= s_rect[4 * k + 1]) & (x < s_rect[4 * k + 3]);
        if (cov) {
            if (s_fill[k] != 0.f) blot = true;
            else erase = true;
        }
    }
    float r0 = blot ? 1.f : (erase ? 0.f : fminf(fmaxf(v0, 0.f), 1.f));
    float r1 = blot ? 1.f : (erase ? 0.f : fminf(fmaxf(v1, 0.f), 1.f));
    float r2 = blot ? 1.f : (erase ? 0.f : fminf(fmaxf(v2, 0.f), 1.f));

    // no barrier needed before overwrite: thread x is the only reader of
    // sbuf[3x..3x+2] after the first sync
    sbuf[x * 3 + 0] = r0;
    sbuf[x * 3 + 1] = r1;
    sbuf[x * 3 + 2] = r2;
    __syncthreads();
    if (threadIdx.x < 192)
        ((float4*)rowp)[threadIdx.x] = ((const float4*)sbuf)[threadIdx.x];
}

extern "C" void kernel_launch(void* const* d_in, const int* in_sizes, int n_in,
                              void* d_out, int out_size, void* d_ws, size_t ws_size,
                              hipStream_t stream) {
    const float* images     = (const float*)d_in[0];
    const float* zoom       = (const float*)d_in[1];
    const float* rot        = (const float*)d_in[2];
    const float* shy        = (const float*)d_in[3];
    const float* ty         = (const float*)d_in[4];
    const float* tx         = (const float*)d_in[5];
    const float* contrast   = (const float*)d_in[6];
    const float* brightness = (const float*)d_in[7];
    const float* fill       = (const float*)d_in[8];
    const int*   hs         = (const int*)d_in[9];
    const int*   ws_        = (const int*)d_in[10];
    const int*   y0         = (const int*)d_in[11];
    const int*   x0         = (const int*)d_in[12];
    float* out = (float*)d_out;

    char* wsb = (char*)d_ws;
    float* coefs = (float*)(wsb + WS_COEFS);
    float* sums  = (float*)(wsb + WS_SUMS);
    int*   rects = (int*)(wsb + WS_RECTS);

    prep_kernel<<<B_, 32, 0, stream>>>(zoom, rot, shy, ty, tx,
                                       hs, ws_, y0, x0, coefs, sums, rects);
    dim3 gridA(64, B_);   // 64 tiles (8x8) per image
    warp_sum_kernel<<<gridA, 256, 0, stream>>>(images, coefs, sums, out);
    finish_kernel<<<B_ * H_, 256, 0, stream>>>(out, sums, rects, fill,
                                               contrast, brightness);
}